// Round 8
// baseline (258.838 us; speedup 1.0000x reference)
//
#include <hip/hip_runtime.h>

#define BB 4
#define NN 16384
#define SS 4096
#define CC 256
#define TLD 132  // gather tile leading dim (words): 128ch + 4 pad, rows 16B-aligned

typedef float f32x4 __attribute__((ext_vector_type(4)));  // for nontemporal builtins

__device__ __forceinline__ bool lexlt(float da, int ia, float db, int ib) {
  // strict (d, idx) lexicographic order — matches jax.lax.top_k tie-break
  return (da < db) || ((da == db) && (ia < ib));
}

// ---------------- Kernel P: pack candidates as {x,y,z,kk} ----------------
// kk = (x*x + y*y) + z*z, np left-to-right order, contract off — byte-identical
// to the staging math previously done in-kernel (proven in R5). 256 KB workspace.
__global__ __launch_bounds__(256) void prep_kernel(const float* __restrict__ kg,
                                                   float4* __restrict__ cand) {
#pragma clang fp contract(off)
  int gid = blockIdx.x * 256 + threadIdx.x;  // 16384 = BB*SS
  int b = gid >> 12, s = gid & 4095;
  const float* kp = kg + ((long)b * SS + s) * 3;
  float x = kp[0], y = kp[1], z = kp[2];
  float kk = (x * x + y * y) + z * z;
  cand[(long)b * SS + s] = make_float4(x, y, z, kk);
}

// ---------------- Kernel A: LDS-free gated scan, lane = query, RQ=2 ----------------
// Grid 512 = b(4) x seg(4) x ngrp(32); 256 thr (4 waves); 2 blocks/CU, 8 waves/CU.
// Each wave owns 128 queries (qA = lane, qB = lane+64) over its segment's 1024 cands.
// Candidates are WAVE-UNIFORM global reads of prepped {x,y,z,kk} -> scalar-load path
// (s_load_dwordx4), zero LDS, zero barriers; L1/L2 serve the 16KB/seg stream.
// Chunk 0 (256 cands): ungated insert seeds top-3. Chunks 1-3: per-query-group gate
// `__any(d < tau)` with tau = d2 frozen per chunk (loop-invariant; a needed insert
// has d < d2_run <= tau so it's never missed; insert body is idempotent for
// non-qualifying lanes). Insert body byte-identical to R0/R6; s ascending per lane.
__global__ __launch_bounds__(256, 2) void scan_kernel(
    const float* __restrict__ qg, const f32x4* __restrict__ cand,
    float4* __restrict__ dpart, int4* __restrict__ ipart) {
#pragma clang fp contract(off)
  const int tid = threadIdx.x;
  const int blk = blockIdx.x;
  const int b = blk >> 7;
  const int seg = (blk >> 5) & 3;
  const int ngrp = blk & 31;
  const int wv = tid >> 6;
  const int lane = tid & 63;
  const int n0 = (ngrp << 9) + (wv << 7);  // 128 queries per wave
  const int qA = n0 + lane;
  const int qB = n0 + 64 + lane;

  // ---- per-lane query data (two queries) ----
  const float* qpA = qg + ((long)b * NN + qA) * 3;
  const float* qpB = qg + ((long)b * NN + qB) * 3;
  float axq = qpA[0], ayq = qpA[1], azq = qpA[2];
  float bxq = qpB[0], byq = qpB[1], bzq = qpB[2];
  float aqq = (axq * axq + ayq * ayq) + azq * azq;  // np sum order
  float bqq = (bxq * bxq + byq * byq) + bzq * bzq;
  float ad0 = 3.4e38f, ad1 = 3.4e38f, ad2 = 3.4e38f;
  float bd0 = 3.4e38f, bd1 = 3.4e38f, bd2 = 3.4e38f;
  int ai0 = 0, ai1 = 0, ai2 = 0;
  int bi0 = 0, bi1 = 0, bi2 = 0;

  const f32x4* cb = cand + (long)b * SS + seg * 1024;
  const int sb = seg * 1024;

  // ---- chunk 0: ungated full insert for both query groups (seeds top-3) ----
#pragma unroll 4
  for (int i = 0; i < 256; ++i) {
    f32x4 kp = cb[i];  // wave-uniform -> scalar load
    const int s = sb + i;
    // exact np replication: d = qq - 2*dot + kk, left-to-right, no contract.
    {
      float dot = (axq * kp.x + ayq * kp.y) + azq * kp.z;
      float d = __builtin_fmaf(dot, -2.0f, aqq) + kp.w;
      bool k2 = d < ad2, k1 = d < ad1, k0 = d < ad0;
      float nd2 = __builtin_amdgcn_fmed3f(d, ad1, ad2);
      float nd1 = __builtin_amdgcn_fmed3f(d, ad0, ad1);
      float nd0 = fminf(d, ad0);
      ai2 = k1 ? ai1 : (k2 ? s : ai2);
      ai1 = k0 ? ai0 : (k1 ? s : ai1);
      ai0 = k0 ? s : ai0;
      ad2 = nd2; ad1 = nd1; ad0 = nd0;
    }
    {
      float dot = (bxq * kp.x + byq * kp.y) + bzq * kp.z;
      float d = __builtin_fmaf(dot, -2.0f, bqq) + kp.w;
      bool k2 = d < bd2, k1 = d < bd1, k0 = d < bd0;
      float nd2 = __builtin_amdgcn_fmed3f(d, bd1, bd2);
      float nd1 = __builtin_amdgcn_fmed3f(d, bd0, bd1);
      float nd0 = fminf(d, bd0);
      bi2 = k1 ? bi1 : (k2 ? s : bi2);
      bi1 = k0 ? bi0 : (k1 ? s : bi1);
      bi0 = k0 ? s : bi0;
      bd2 = nd2; bd1 = nd1; bd0 = nd0;
    }
  }

  // ---- chunks 1-3: gated, tau frozen per chunk per query group ----
  for (int c = 1; c < 4; ++c) {
    const float tauA = ad2;  // per-lane; d2_run <= tau within the chunk
    const float tauB = bd2;
    const int base = c * 256;
#pragma unroll 8
    for (int i = 0; i < 256; ++i) {
      f32x4 kp = cb[base + i];  // wave-uniform -> scalar load
      const int s = sb + base + i;
      float dotA = (axq * kp.x + ayq * kp.y) + azq * kp.z;
      float dA = __builtin_fmaf(dotA, -2.0f, aqq) + kp.w;
      float dotB = (bxq * kp.x + byq * kp.y) + bzq * kp.z;
      float dB = __builtin_fmaf(dotB, -2.0f, bqq) + kp.w;
      // needed insert satisfies d < d2_run <= tau -> gate never misses one
      if (__builtin_expect(__any(dA < tauA), 0)) {
        bool k2 = dA < ad2, k1 = dA < ad1, k0 = dA < ad0;
        float nd2 = __builtin_amdgcn_fmed3f(dA, ad1, ad2);
        float nd1 = __builtin_amdgcn_fmed3f(dA, ad0, ad1);
        float nd0 = fminf(dA, ad0);
        ai2 = k1 ? ai1 : (k2 ? s : ai2);
        ai1 = k0 ? ai0 : (k1 ? s : ai1);
        ai0 = k0 ? s : ai0;
        ad2 = nd2; ad1 = nd1; ad0 = nd0;
      }
      if (__builtin_expect(__any(dB < tauB), 0)) {
        bool k2 = dB < bd2, k1 = dB < bd1, k0 = dB < bd0;
        float nd2 = __builtin_amdgcn_fmed3f(dB, bd1, bd2);
        float nd1 = __builtin_amdgcn_fmed3f(dB, bd0, bd1);
        float nd0 = fminf(dB, bd0);
        bi2 = k1 ? bi1 : (k2 ? s : bi2);
        bi1 = k0 ? bi0 : (k1 ? s : bi1);
        bi0 = k0 ? s : bi0;
        bd2 = nd2; bd1 = nd1; bd0 = nd0;
      }
    }
  }

  // ---- write both lanes' partials (no intra-block merge needed) ----
  long gidA = (long)b * NN + qA;
  long gidB = (long)b * NN + qB;
  dpart[gidA * 4 + seg] = make_float4(ad0, ad1, ad2, 0.0f);
  ipart[gidA * 4 + seg] = make_int4(ai0, ai1, ai2, 0);
  dpart[gidB * 4 + seg] = make_float4(bd0, bd1, bd2, 0.0f);
  ipart[gidB * 4 + seg] = make_int4(bi0, bi1, bi2, 0);
}

// ---------------- Kernel B: merge partials + gather + transpose ----------------
// Verbatim R3 (v3b): XCD-affinity decomposition, measured ~21 us. Grid 2048;
// round-robin dispatch -> XCD = bid&7; each XCD owns one (batch, channel-half):
// per-XCD V working set 2 MB < 4 MB L2. NT stores keep writes from evicting V.
__global__ __launch_bounds__(256, 4) void gather_kernel(
    const float* __restrict__ vg, const float4* __restrict__ dpart,
    const int4* __restrict__ ipart, float* __restrict__ outg) {
#pragma clang fp contract(off)
  __shared__ __align__(16) float tile[64 * TLD];  // 33.8 KB
  __shared__ float sw[64][3];
  __shared__ int si[64][3];

  const int tid = threadIdx.x;
  const int bid = blockIdx.x;
  const int xcd = bid & 7;     // dispatch round-robin: block -> XCD
  const int b = xcd >> 1;      // 2 XCDs per batch
  const int chunk = xcd & 1;   // which 128-channel half this XCD handles
  const int nblk = bid >> 3;   // 0..255
  const int n0 = nblk << 6;    // 64 queries per block

  if (tid < 64) {
    long gid = (long)b * NN + n0 + tid;
    float D0 = 3.4e38f, D1 = 3.4e38f, D2 = 3.4e38f;
    int I0 = -1, I1 = -1, I2 = -1;
#pragma unroll
    for (int seg = 0; seg < 4; ++seg) {
      float4 dv = dpart[gid * 4 + seg];
      int4 iv = ipart[gid * 4 + seg];
      float ds_[3] = {dv.x, dv.y, dv.z};
      int is_[3] = {iv.x, iv.y, iv.z};
      for (int r = 0; r < 3; ++r) {
        float d = ds_[r];
        int s = is_[r];
        if (lexlt(d, s, D2, I2)) {
          if (lexlt(d, s, D1, I1)) {
            D2 = D1; I2 = I1;
            if (lexlt(d, s, D0, I0)) { D1 = D0; I1 = I0; D0 = d; I0 = s; }
            else { D1 = d; I1 = s; }
          } else { D2 = d; I2 = s; }
        }
      }
    }
    // weights exactly as ref: recip = 1/(d+1e-8) on ascending dists, then normalize
    float r0 = 1.0f / (D0 + 1e-8f);
    float r1 = 1.0f / (D1 + 1e-8f);
    float r2 = 1.0f / (D2 + 1e-8f);
    float rs = (r0 + r1) + r2;
    sw[tid][0] = r0 / rs; sw[tid][1] = r1 / rs; sw[tid][2] = r2 / rs;
    si[tid][0] = I0; si[tid][1] = I1; si[tid][2] = I2;
  }
  __syncthreads();

  const int wv = tid >> 6;      // wave id 0..3 -> owns queries wv*16 .. wv*16+15
  const int lane = tid & 63;
  const int qh = lane >> 5;     // half-wave: which of 2 queries this iteration
  const int slot = lane & 31;   // f4 slot within the 128-channel half
  const float* vb = vg + (long)b * SS * CC + chunk * 128;

#pragma unroll 4
  for (int it = 0; it < 8; ++it) {
    int qs = wv * 16 + it * 2 + qh;
    float w0 = sw[qs][0], w1 = sw[qs][1], w2 = sw[qs][2];
    const float4* r0p = (const float4*)(vb + (long)si[qs][0] * CC);
    const float4* r1p = (const float4*)(vb + (long)si[qs][1] * CC);
    const float4* r2p = (const float4*)(vb + (long)si[qs][2] * CC);
    float4 a0 = r0p[slot], a1 = r1p[slot], a2 = r2p[slot];
    float4 acc;
    acc.x = (w0 * a0.x + w1 * a1.x) + w2 * a2.x;
    acc.y = (w0 * a0.y + w1 * a1.y) + w2 * a2.y;
    acc.z = (w0 * a0.z + w1 * a1.z) + w2 * a2.z;
    acc.w = (w0 * a0.w + w1 * a1.w) + w2 * a2.w;
    *(float4*)&tile[qs * TLD + slot * 4] = acc;
  }
  __syncthreads();

  // store: 128 channels x 64 n; each thread assembles float4 along n (non-temporal)
  {
    const int nf = tid & 15;   // f4 group along n
    const int cb0 = tid >> 4;  // channel base 0..15
    const int q0 = nf << 2;    // first of 4 consecutive queries (n)
#pragma unroll 2
    for (int it = 0; it < 8; ++it) {
      int cl = cb0 + it * 16;           // channel within half 0..127
      int cch = (chunk << 7) + cl;      // global channel
      f32x4 val;
      val.x = tile[(q0 + 0) * TLD + cl];
      val.y = tile[(q0 + 1) * TLD + cl];
      val.z = tile[(q0 + 2) * TLD + cl];
      val.w = tile[(q0 + 3) * TLD + cl];
      __builtin_nontemporal_store(
          val, (f32x4*)&outg[((long)(b * CC + cch)) * NN + n0 + q0]);
    }
  }
}

extern "C" void kernel_launch(void* const* d_in, const int* in_sizes, int n_in,
                              void* d_out, int out_size, void* d_ws, size_t ws_size,
                              hipStream_t stream) {
  const float* q = (const float*)d_in[0];
  const float* k = (const float*)d_in[1];
  const float* v = (const float*)d_in[2];
  float* out = (float*)d_out;
  float4* dpart = (float4*)d_ws;                                          // 4 MB
  int4* ipart = (int4*)((char*)d_ws + (size_t)BB * NN * 4 * 16);          // 4 MB
  float4* cand = (float4*)((char*)d_ws + 2 * (size_t)BB * NN * 4 * 16);   // 256 KB
  hipLaunchKernelGGL(prep_kernel, dim3(64), dim3(256), 0, stream, k, cand);
  hipLaunchKernelGGL(scan_kernel, dim3(512), dim3(256), 0, stream, q,
                     (const f32x4*)cand, dpart, ipart);
  hipLaunchKernelGGL(gather_kernel, dim3(2048), dim3(256), 0, stream, v, dpart, ipart, out);
}

// Round 9
// 207.814 us; speedup vs baseline: 1.2455x; 1.2455x over previous
//
#include <hip/hip_runtime.h>

#define BB 4
#define NN 16384
#define SS 4096
#define CC 256
#define TLD 132  // gather tile leading dim (words): 128ch + 4 pad, rows 16B-aligned

typedef float f32x4 __attribute__((ext_vector_type(4)));  // for nontemporal builtins

__device__ __forceinline__ bool lexlt(float da, int ia, float db, int ib) {
  // strict (d, idx) lexicographic order — matches jax.lax.top_k tie-break
  return (da < db) || ((da == db) && (ia < ib));
}

// exact np replication: d = qq - 2*dot + kk, left-to-right, no contract
#define DIST(kp) ({                                        \
  float _dot = (qx * (kp).x + qy * (kp).y) + qz * (kp).z;  \
  __builtin_fmaf(_dot, -2.0f, qq) + (kp).w;                \
})

// byte-identical top-3 insert (idempotent when dd >= d2)
#define INSERT(dd, ss) do {                                \
  bool _k2 = (dd) < d2, _k1 = (dd) < d1, _k0 = (dd) < d0;  \
  float _nd2 = __builtin_amdgcn_fmed3f((dd), d1, d2);      \
  float _nd1 = __builtin_amdgcn_fmed3f((dd), d0, d1);      \
  float _nd0 = fminf((dd), d0);                            \
  i2 = _k1 ? i1 : (_k2 ? (ss) : i2);                       \
  i1 = _k0 ? i0 : (_k1 ? (ss) : i1);                       \
  i0 = _k0 ? (ss) : i0;                                    \
  d2 = _nd2; d1 = _nd1; d0 = _nd0;                         \
} while (0)

// ---------------- Kernel A: bundle-gated top-3 scan, lane = query ----------------
// Grid 1024 = b(4) x seg(4) x qgrp(64); 256 thr (4 waves); 4 blocks/CU, 16 waves/CU
// (R6 geometry — proven 131.5 us). Each wave owns 64 queries over 1024 staged cands.
// R9 change: gate is BUNDLED per 16 candidates. Dist phase is branch-free (16
// ds_read_b128 + 112 FLOPs, pipelines like the R0 straight-line loop); a 16-bit
// wave-uniform mask (bit j = __any(dv[j] < tau), tau = d2 frozen at bundle start)
// drives a scalar-branch insert sweep with compile-time dv[] indices. Executed-op
// count == R6; issue structure == R0. Gate exact: needed insert has
// d < d2_run <= tau -> bit set; insert body idempotent & byte-identical; s ascending.
__global__ __launch_bounds__(256, 4) void scan_kernel(
    const float* __restrict__ qg, const float* __restrict__ kg,
    float4* __restrict__ dpart, int4* __restrict__ ipart) {
#pragma clang fp contract(off)
  __shared__ __align__(16) float4 kpts[1024];  // 16 KB

  const int tid = threadIdx.x;
  const int blk = blockIdx.x;
  const int b = blk >> 8;
  const int seg = (blk >> 6) & 3;
  const int n0 = (blk & 63) << 8;  // 256 queries per block
  const int wv = tid >> 6;
  const int lane = tid & 63;
  const int q = n0 + wv * 64 + lane;  // this lane's query

  // ---- stage this segment's 1024 points as {x,y,z,kk} ----
  {
    const float* kb = kg + ((long)b * SS + (long)seg * 1024) * 3;
    const float4* src = (const float4*)kb + tid * 3;
    float4 f0 = src[0], f1 = src[1], f2 = src[2];
    float px[4] = {f0.x, f0.w, f1.z, f2.y};
    float py[4] = {f0.y, f1.x, f1.w, f2.z};
    float pz[4] = {f0.z, f1.y, f2.x, f2.w};
#pragma unroll
    for (int m = 0; m < 4; ++m) {
      float kk = (px[m] * px[m] + py[m] * py[m]) + pz[m] * pz[m];  // np order
      kpts[tid * 4 + m] = make_float4(px[m], py[m], pz[m], kk);
    }
  }

  const float* qp = qg + ((long)b * NN + q) * 3;
  float qx = qp[0], qy = qp[1], qz = qp[2];
  float qq = (qx * qx + qy * qy) + qz * qz;  // np sum order
  float d0 = 3.4e38f, d1 = 3.4e38f, d2 = 3.4e38f;
  int i0 = 0, i1 = 0, i2 = 0;
  __syncthreads();

  const int sb = seg * 1024;

  // ---- prefix: 16 bundles of 16, ungated (seeds the top-3) ----
  for (int bdl = 0; bdl < 16; ++bdl) {
    const int base = bdl << 4;
    float dv[16];
#pragma unroll
    for (int sj = 0; sj < 4; ++sj) {  // 4 cands per sub-bundle bounds VGPR pressure
      float4 ka = kpts[base + 4 * sj + 0];
      float4 kb_ = kpts[base + 4 * sj + 1];
      float4 kc = kpts[base + 4 * sj + 2];
      float4 kd = kpts[base + 4 * sj + 3];
      dv[4 * sj + 0] = DIST(ka);
      dv[4 * sj + 1] = DIST(kb_);
      dv[4 * sj + 2] = DIST(kc);
      dv[4 * sj + 3] = DIST(kd);
    }
#pragma unroll
    for (int j = 0; j < 16; ++j) INSERT(dv[j], sb + base + j);
  }

  // ---- gated: 48 bundles of 16, tau frozen per bundle ----
  for (int bdl = 16; bdl < 64; ++bdl) {
    const int base = bdl << 4;
    const float tau = d2;  // per-lane; d2_run <= tau within the bundle
    float dv[16];
    unsigned msk = 0;
#pragma unroll
    for (int sj = 0; sj < 4; ++sj) {
      float4 ka = kpts[base + 4 * sj + 0];
      float4 kb_ = kpts[base + 4 * sj + 1];
      float4 kc = kpts[base + 4 * sj + 2];
      float4 kd = kpts[base + 4 * sj + 3];
      dv[4 * sj + 0] = DIST(ka);
      dv[4 * sj + 1] = DIST(kb_);
      dv[4 * sj + 2] = DIST(kc);
      dv[4 * sj + 3] = DIST(kd);
    }
#pragma unroll
    for (int j = 0; j < 16; ++j) msk |= (__any(dv[j] < tau) ? 1u : 0u) << j;
    if (msk) {
#pragma unroll
      for (int j = 0; j < 16; ++j) {
        if (msk & (1u << j)) INSERT(dv[j], sb + base + j);
      }
    }
  }

  // ---- write this lane's partial (no intra-block merge needed) ----
  long gid = (long)b * NN + q;
  dpart[gid * 4 + seg] = make_float4(d0, d1, d2, 0.0f);
  ipart[gid * 4 + seg] = make_int4(i0, i1, i2, 0);
}

// ---------------- Kernel B: merge partials + gather + transpose ----------------
// Verbatim R3 (v3b): XCD-affinity decomposition, measured ~21 us. Grid 2048;
// round-robin dispatch -> XCD = bid&7; each XCD owns one (batch, channel-half):
// per-XCD V working set 2 MB < 4 MB L2. NT stores keep writes from evicting V.
__global__ __launch_bounds__(256, 4) void gather_kernel(
    const float* __restrict__ vg, const float4* __restrict__ dpart,
    const int4* __restrict__ ipart, float* __restrict__ outg) {
#pragma clang fp contract(off)
  __shared__ __align__(16) float tile[64 * TLD];  // 33.8 KB
  __shared__ float sw[64][3];
  __shared__ int si[64][3];

  const int tid = threadIdx.x;
  const int bid = blockIdx.x;
  const int xcd = bid & 7;     // dispatch round-robin: block -> XCD
  const int b = xcd >> 1;      // 2 XCDs per batch
  const int chunk = xcd & 1;   // which 128-channel half this XCD handles
  const int nblk = bid >> 3;   // 0..255
  const int n0 = nblk << 6;    // 64 queries per block

  if (tid < 64) {
    long gid = (long)b * NN + n0 + tid;
    float D0 = 3.4e38f, D1 = 3.4e38f, D2 = 3.4e38f;
    int I0 = -1, I1 = -1, I2 = -1;
#pragma unroll
    for (int seg = 0; seg < 4; ++seg) {
      float4 dv = dpart[gid * 4 + seg];
      int4 iv = ipart[gid * 4 + seg];
      float ds_[3] = {dv.x, dv.y, dv.z};
      int is_[3] = {iv.x, iv.y, iv.z};
      for (int r = 0; r < 3; ++r) {
        float d = ds_[r];
        int s = is_[r];
        if (lexlt(d, s, D2, I2)) {
          if (lexlt(d, s, D1, I1)) {
            D2 = D1; I2 = I1;
            if (lexlt(d, s, D0, I0)) { D1 = D0; I1 = I0; D0 = d; I0 = s; }
            else { D1 = d; I1 = s; }
          } else { D2 = d; I2 = s; }
        }
      }
    }
    // weights exactly as ref: recip = 1/(d+1e-8) on ascending dists, then normalize
    float r0 = 1.0f / (D0 + 1e-8f);
    float r1 = 1.0f / (D1 + 1e-8f);
    float r2 = 1.0f / (D2 + 1e-8f);
    float rs = (r0 + r1) + r2;
    sw[tid][0] = r0 / rs; sw[tid][1] = r1 / rs; sw[tid][2] = r2 / rs;
    si[tid][0] = I0; si[tid][1] = I1; si[tid][2] = I2;
  }
  __syncthreads();

  const int wv = tid >> 6;      // wave id 0..3 -> owns queries wv*16 .. wv*16+15
  const int lane = tid & 63;
  const int qh = lane >> 5;     // half-wave: which of 2 queries this iteration
  const int slot = lane & 31;   // f4 slot within the 128-channel half
  const float* vb = vg + (long)b * SS * CC + chunk * 128;

#pragma unroll 4
  for (int it = 0; it < 8; ++it) {
    int qs = wv * 16 + it * 2 + qh;
    float w0 = sw[qs][0], w1 = sw[qs][1], w2 = sw[qs][2];
    const float4* r0p = (const float4*)(vb + (long)si[qs][0] * CC);
    const float4* r1p = (const float4*)(vb + (long)si[qs][1] * CC);
    const float4* r2p = (const float4*)(vb + (long)si[qs][2] * CC);
    float4 a0 = r0p[slot], a1 = r1p[slot], a2 = r2p[slot];
    float4 acc;
    acc.x = (w0 * a0.x + w1 * a1.x) + w2 * a2.x;
    acc.y = (w0 * a0.y + w1 * a1.y) + w2 * a2.y;
    acc.z = (w0 * a0.z + w1 * a1.z) + w2 * a2.z;
    acc.w = (w0 * a0.w + w1 * a1.w) + w2 * a2.w;
    *(float4*)&tile[qs * TLD + slot * 4] = acc;
  }
  __syncthreads();

  // store: 128 channels x 64 n; each thread assembles float4 along n (non-temporal)
  {
    const int nf = tid & 15;   // f4 group along n
    const int cb0 = tid >> 4;  // channel base 0..15
    const int q0 = nf << 2;    // first of 4 consecutive queries (n)
#pragma unroll 2
    for (int it = 0; it < 8; ++it) {
      int cl = cb0 + it * 16;           // channel within half 0..127
      int cch = (chunk << 7) + cl;      // global channel
      f32x4 val;
      val.x = tile[(q0 + 0) * TLD + cl];
      val.y = tile[(q0 + 1) * TLD + cl];
      val.z = tile[(q0 + 2) * TLD + cl];
      val.w = tile[(q0 + 3) * TLD + cl];
      __builtin_nontemporal_store(
          val, (f32x4*)&outg[((long)(b * CC + cch)) * NN + n0 + q0]);
    }
  }
}

extern "C" void kernel_launch(void* const* d_in, const int* in_sizes, int n_in,
                              void* d_out, int out_size, void* d_ws, size_t ws_size,
                              hipStream_t stream) {
  const float* q = (const float*)d_in[0];
  const float* k = (const float*)d_in[1];
  const float* v = (const float*)d_in[2];
  float* out = (float*)d_out;
  float4* dpart = (float4*)d_ws;                                          // 4 MB
  int4* ipart = (int4*)((char*)d_ws + (size_t)BB * NN * 4 * 16);          // 4 MB
  hipLaunchKernelGGL(scan_kernel, dim3(1024), dim3(256), 0, stream, q, k, dpart, ipart);
  hipLaunchKernelGGL(gather_kernel, dim3(2048), dim3(256), 0, stream, v, dpart, ipart, out);
}